// Round 9
// baseline (174.668 us; speedup 1.0000x reference)
//
#include <hip/hip_runtime.h>
#include <cstdint>

// VectorQuantizer: x[16,1024,16,16] f32, codebook[1,8192,1024], values[1,8192,1024]
// Round 16 == Round 15 (broker timeout; single-barrier loop desk-audited, held).
// r13 HW baseline: passed, absmax 0.0, total 172.9 us, dist 44.2 us.
// r15 change under test: ONE barrier per 128B-K iteration (16 -> 8 barriers):
//   vmcnt(0) [loads issued a full iter ago] -> s_barrier -> sched_barrier(0) ->
//   issue 8 gloads for iter i+1 (post-barrier: WAR-safe) -> 24 ds_read + 64
//   MFMA under one setprio window. Epilogue: r13-verified 32-bit DPP merges.

constexpr int Dd = 1024;   // feature dim (GEMM K)
constexpr int Nn = 256;    // tokens per batch
constexpr int Bb = 16;     // batch
constexpr int Kk = 8192;   // codes (GEMM N)
constexpr int Mm = 4096;   // tokens (GEMM M)
constexpr int STAGES = Dd / 64;     // 16 x 64B K-chunks (kb index)
constexpr int NITER = STAGES / 2;   // 8 main-loop iterations, 128B K per iter
constexpr int NCHUNK = Kk / 64;     // 128 chunks of 64 codes
constexpr int NCAND = NCHUNK * 2;   // 256 candidates per token
constexpr float QS = 24.0f;         // quant scale
constexpr float SC2 = 2.0f / (QS * QS);

typedef __attribute__((ext_vector_type(4))) int vi4;       // 16 i8 = 4 VGPRs
typedef unsigned long long u64;
typedef unsigned char uchar;

__device__ __forceinline__ void gload16(const void* g, void* l) {
    // async global->LDS; lds dest = wave-uniform base + lane*16 (verified r2-r5)
    __builtin_amdgcn_global_load_lds((const __attribute__((address_space(1))) uint32_t*)g,
                                     (__attribute__((address_space(3))) uint32_t*)l, 16, 0, 0);
}

// DPP row_ror:N within 16-lane rows (VALU-rate cross-lane; all lanes active).
template <int CTRL>
__device__ __forceinline__ uint32_t rot16(uint32_t v) {
    return (uint32_t)__builtin_amdgcn_update_dpp(0, (int)v, CTRL, 0xF, 0xF, true);
}
template <int CTRL>
__device__ __forceinline__ u64 rot16_64(u64 v) {
    uint32_t lo = rot16<CTRL>((uint32_t)v);
    uint32_t hi = rot16<CTRL>((uint32_t)(v >> 32));
    return ((u64)hi << 32) | lo;
}

__device__ __forceinline__ void mm2u(uint32_t& a, uint32_t& b) {  // sort pair asc
    uint32_t lo = a < b ? a : b;
    uint32_t hi = a < b ? b : a;
    a = lo; b = hi;
}
// merge sorted pairs: (a1,a2) <- top-2 (smallest) of {a1,a2,b1,b2}
__device__ __forceinline__ void merge2u(uint32_t& a1, uint32_t& a2, uint32_t b1,
                                        uint32_t b2) {
    uint32_t t1 = a1 < b1 ? a1 : b1;
    uint32_t hi = a1 < b1 ? b1 : a1;
    uint32_t l2 = a2 < b2 ? a2 : b2;
    a2 = hi < l2 ? hi : l2;
    a1 = t1;
}

__device__ __forceinline__ int q8(float v) {  // round-to-nearest, clamp [-127,127]
    int qi = (int)rintf(v * QS);
    qi = qi > 127 ? 127 : (qi < -127 ? -127 : qi);
    return qi & 0xFF;
}
__device__ __forceinline__ int pk4i(float a, float b, float c, float d) {
    return q8(a) | (q8(b) << 8) | (q8(c) << 16) | (q8(d) << 24);
}

// Fragment-order packed layout (A and B identical; verified-symmetric for the
// 16x16 family): P[(g*16 + kb)*64 + lane]*16B, g = row>>4, kb = k>>6,
// lane = (row&15) | (q<<4), q = (k>>4)&3, byte j = k&15.

// ---------- prep ----------
// grid 1024: [0,512) cb->Bpk + esq; [512,1024) x->Apk (+xT when non-null)
__global__ __launch_bounds__(256) void prep_kernel(const float* __restrict__ x,
                                                   const float* __restrict__ cb,
                                                   uchar* __restrict__ Apk,
                                                   uchar* __restrict__ Bpk,
                                                   float* __restrict__ esq,
                                                   float* __restrict__ xT) {
    const int tid = threadIdx.x;
    if (blockIdx.x < 512) {  // codebook: 16 codes/block; thread=(rl 4b hi, seg 4b lo)
        const int rl = tid >> 4, seg = tid & 15;   // seg == kb
        const int code = blockIdx.x * 16 + rl;
        const float* src = cb + (size_t)code * Dd + seg * 64;
        float v[64];
        float ss = 0.f;
#pragma unroll
        for (int j = 0; j < 64; j += 4) {
            float4 f = *(const float4*)&src[j];
            v[j] = f.x; v[j + 1] = f.y; v[j + 2] = f.z; v[j + 3] = f.w;
            ss += f.x * f.x + f.y * f.y + f.z * f.z + f.w * f.w;
        }
#pragma unroll
        for (int off = 8; off; off >>= 1) ss += __shfl_down(ss, off, 16);
        if (seg == 0) esq[code] = ss;
        const int g = code >> 4, rlane = code & 15;
#pragma unroll
        for (int q = 0; q < 4; ++q) {
            int o[4];
#pragma unroll
            for (int w4 = 0; w4 < 4; ++w4) {
                const int j = q * 16 + w4 * 4;
                o[w4] = pk4i(v[j], v[j + 1], v[j + 2], v[j + 3]);
            }
            *(uint4*)&Bpk[((size_t)(g * 16 + seg) * 64 + (rlane | (q << 4))) * 16] =
                *(const uint4*)o;
        }
    } else {  // x -> Apk (+ xT): block=(b, d-chunk of 32), thread=n
        const int bb = blockIdx.x - 512;
        const int b = bb >> 5, d0 = (bb & 31) * 32, n = tid;
        const int t = b * 256 + n;
        const float* xb = x + (size_t)b * Dd * Nn + n;
        const int g = t >> 4, rlane = t & 15, kb = d0 >> 6, qbase = (d0 & 32) >> 4;
        float v[32];
#pragma unroll
        for (int jj = 0; jj < 32; ++jj) v[jj] = xb[(size_t)(d0 + jj) * Nn];
#pragma unroll
        for (int h = 0; h < 2; ++h) {
            int o[4];
#pragma unroll
            for (int w4 = 0; w4 < 4; ++w4) {
                const int j = h * 16 + w4 * 4;
                o[w4] = pk4i(v[j], v[j + 1], v[j + 2], v[j + 3]);
            }
            *(uint4*)&Apk[((size_t)(g * 16 + kb) * 64 + (rlane | ((qbase + h) << 4))) * 16] =
                *(const uint4*)o;
        }
        if (xT) {  // bigws only: write the already-loaded slice to xT
            float* row = xT + (size_t)t * Dd + d0;
#pragma unroll
            for (int jj = 0; jj < 32; jj += 4) {
                float4 f;
                f.x = v[jj]; f.y = v[jj + 1]; f.z = v[jj + 2]; f.w = v[jj + 3];
                *(float4*)&row[jj] = f;
            }
        }
    }
}

// ---------- x -> xT fp32 (fallback path, AFTER dist; aliases Apk/Bpk region) ----------
__global__ __launch_bounds__(256) void transx_kernel(const float* __restrict__ x,
                                                     float* __restrict__ xT) {
    const int n = threadIdx.x, b = blockIdx.x, d0 = blockIdx.y * 32;
    const float* xb = x + (size_t)b * Dd * Nn + n;
    float* row = xT + (size_t)(b * Nn + n) * Dd + d0;
#pragma unroll
    for (int jj = 0; jj < 8; ++jj) {
        float4 v;
        v.x = xb[(size_t)(d0 + jj * 4 + 0) * Nn];
        v.y = xb[(size_t)(d0 + jj * 4 + 1) * Nn];
        v.z = xb[(size_t)(d0 + jj * 4 + 2) * Nn];
        v.w = xb[(size_t)(d0 + jj * 4 + 3) * Nn];
        *(float4*)&row[jj * 4] = v;
    }
}

// ---------- i8 MFMA distance: 256x256 tile, single-barrier iterations ----------
// grid (32, 16), 512 threads = 8 waves (wm in [0,2), wn in [0,4)).
// Wave owns a 128x64 output tile = 8x4 fragments of 16x16x64 MFMA.
// LDS: double buffer x 2 K-tiles(64B) x 16 groups x 1KB for A and for B = 128 KB.
// Main loop: 8 iters, 128B K each, ONE barrier per iter:
//   vmcnt(0) [iter i's 8 loads, issued a full iter ago -- free drain] ->
//   s_barrier -> sched_barrier(0) -> issue 8 gloads for iter i+1 (post-barrier:
//   WAR-safe vs buf^1's last readers) -> 24 ds_read_b128 + 64 MFMA, setprio(1).
// No dangling DMA: last issue at i=6 is waited at i=7's vmcnt(0).
__global__ __launch_bounds__(512, 2) void mfma_dist_kernel(const uchar* __restrict__ Apk,
                                                           const uchar* __restrict__ Bpk,
                                                           const float* __restrict__ esq,
                                                           u64* __restrict__ cand) {
    __shared__ uchar As[2 * 2 * 16 * 1024];  // [buf][kt][group][1KB]
    __shared__ uchar Bs[2 * 2 * 16 * 1024];

    const int tid = threadIdx.x, lane = tid & 63, w = tid >> 6;
    const int wm = w >> 2, wn = w & 3;
    const int nBase = blockIdx.x * 256, mBase = blockIdx.y * 256;
    const int gA = blockIdx.y * 16, gB = blockIdx.x * 16;  // global 16-row group bases

    vi4 acc[8][4];
#pragma unroll
    for (int i = 0; i < 8; ++i)
#pragma unroll
        for (int j = 0; j < 4; ++j) acc[i][j] = (vi4)0;

    // Staging assignment: waves 0-3 stage A groups (w&3)*4..+3, waves 4-7 stage B.
    const uchar* gmat = (w < 4) ? Apk : Bpk;
    const int gBase = ((w < 4) ? gA : gB) + (w & 3) * 4;
    const uchar* gsrc = gmat + (size_t)gBase * 16384 + (size_t)lane * 16;
    uchar* swave = ((w < 4) ? As : Bs) + (w & 3) * 4096;  // + buf*32768 + kt*16384 + r*1024

    // issue both kt sub-tiles of iteration it into buffer buf
    auto stage_iter = [&](int buf, int it) {
#pragma unroll
        for (int kt = 0; kt < 2; ++kt) {
            const int kb = 2 * it + kt;
            uchar* ldst = swave + buf * 32768 + kt * 16384;
#pragma unroll
            for (int r = 0; r < 4; ++r)
                gload16(gsrc + (size_t)(r * 16 + kb) * 1024, ldst + r * 1024);
        }
    };

    auto compute = [&](int buf, int kt) {
        const uchar* ab = As + buf * 32768 + kt * 16384;
        const uchar* bb = Bs + buf * 32768 + kt * 16384;
        vi4 af[8], bf[4];
#pragma unroll
        for (int mi = 0; mi < 8; ++mi)
            af[mi] = *(const vi4*)&ab[((wm * 8 + mi) * 64 + lane) * 16];
#pragma unroll
        for (int ni = 0; ni < 4; ++ni)
            bf[ni] = *(const vi4*)&bb[((wn * 4 + ni) * 64 + lane) * 16];
#pragma unroll
        for (int mi = 0; mi < 8; ++mi)
#pragma unroll
            for (int ni = 0; ni < 4; ++ni)
                acc[mi][ni] = __builtin_amdgcn_mfma_i32_16x16x64_i8(
                    af[mi], bf[ni], acc[mi][ni], 0, 0, 0);
    };

    // prologue: stage iter 0 into buf 0
    stage_iter(0, 0);

    for (int i = 0; i < NITER; ++i) {
        const int buf = i & 1;
        asm volatile("s_waitcnt vmcnt(0)" ::: "memory");  // iter i's loads done
        __builtin_amdgcn_s_barrier();                     // publish to all waves
        __builtin_amdgcn_sched_barrier(0);                // pin everything below
        if (i + 1 < NITER) stage_iter(buf ^ 1, i + 1);    // post-barrier: WAR-safe
        __builtin_amdgcn_s_setprio(1);
        compute(buf, 0);
        compute(buf, 1);
        __builtin_amdgcn_s_setprio(0);
    }

    // Epilogue. C/D: col = lane&15 (+ni*16), row = (lane>>4)*4 + reg.
    // score = max(esq - (2/s^2)*dot, 0) >= 0 -> raw bits order = float order.
    // 32-bit key = (score_bits & ~0x3F) | (ni*16 | lane&15).
    const int chunk = blockIdx.x * 4 + wn;
    const uint32_t cbase = (uint32_t)(nBase + wn * 64);
    float e4[4];
#pragma unroll
    for (int ni = 0; ni < 4; ++ni) e4[ni] = esq[cbase + ni * 16 + (lane & 15)];
#pragma unroll
    for (int mi = 0; mi < 8; ++mi) {
#pragma unroll
        for (int reg = 0; reg < 4; ++reg) {
            uint32_t p[4];
#pragma unroll
            for (int ni = 0; ni < 4; ++ni) {
                float s = fmaxf(fmaf(-SC2, (float)acc[mi][ni][reg], e4[ni]), 0.f);
                p[ni] = (__float_as_uint(s) & 0xFFFFFFC0u) |
                        (uint32_t)(ni * 16 + (lane & 15));
            }
            mm2u(p[0], p[1]); mm2u(p[2], p[3]);
            merge2u(p[0], p[1], p[2], p[3]);
            uint32_t t1 = p[0], t2 = p[1];
            // DPP rotate-merge within the 16-lane row (disjoint windows 1,2,4,8)
            { uint32_t o1 = rot16<0x121>(t1), o2 = rot16<0x121>(t2);
              merge2u(t1, t2, o1, o2); }
            { uint32_t o1 = rot16<0x122>(t1), o2 = rot16<0x122>(t2);
              merge2u(t1, t2, o1, o2); }
            { uint32_t o1 = rot16<0x124>(t1), o2 = rot16<0x124>(t2);
              merge2u(t1, t2, o1, o2); }
            { uint32_t o1 = rot16<0x128>(t1), o2 = rot16<0x128>(t2);
              merge2u(t1, t2, o1, o2); }
            if ((lane & 15) == 0) {
                const int t = mBase + wm * 128 + mi * 16 + (lane >> 4) * 4 + reg;
                cand[(size_t)t * NCAND + chunk * 2 + 0] =
                    ((u64)(t1 & 0xFFFFFFC0u) << 32) | (cbase + (t1 & 63u));
                cand[(size_t)t * NCAND + chunk * 2 + 1] =
                    ((u64)(t2 & 0xFFFFFFC0u) << 32) | (cbase + (t2 & 63u));
            }
        }
    }
}

// ---------- fused select(top-4 of 256) + exact fp32 rescore ----------
__global__ __launch_bounds__(256) void selres_kernel(const u64* __restrict__ cand,
                                                     const float* __restrict__ xT,
                                                     const float* __restrict__ cb,
                                                     const float* __restrict__ esq,
                                                     int* __restrict__ fidx) {
    __shared__ u64 wtop[4][4];
    __shared__ int cs[4];
    __shared__ float red[4][4];
    const int t = blockIdx.x, tid = threadIdx.x, lane = tid & 63, w = tid >> 6;
    u64 v = cand[(size_t)t * NCAND + tid];
#pragma unroll
    for (int rd = 0; rd < 4; ++rd) {  // per-wave top-4 (u64 min, bit-identical)
        u64 m = v;
        { u64 o = rot16_64<0x121>(m); m = m < o ? m : o; }
        { u64 o = rot16_64<0x122>(m); m = m < o ? m : o; }
        { u64 o = rot16_64<0x124>(m); m = m < o ? m : o; }
        { u64 o = rot16_64<0x128>(m); m = m < o ? m : o; }
        { u64 o = __shfl_xor(m, 16, 64); m = m < o ? m : o; }
        { u64 o = __shfl_xor(m, 32, 64); m = m < o ? m : o; }
        if (lane == 0) wtop[w][rd] = m;
        if (v == m) v = ~0ULL;  // packed keys unique per token
    }
    __syncthreads();
    if (tid == 0) {  // merge 16 -> global top-4
        u64 a[16];
#pragma unroll
        for (int i = 0; i < 16; ++i) a[i] = wtop[i >> 2][i & 3];
#pragma unroll
        for (int rd = 0; rd < 4; ++rd) {
            int bi = 0;
            u64 m = a[0];
#pragma unroll
            for (int i = 1; i < 16; ++i)
                if (a[i] < m) { m = a[i]; bi = i; }
            cs[rd] = (int)(uint32_t)m;
            a[bi] = ~0ULL;
        }
    }
    __syncthreads();
    int c[4];
#pragma unroll
    for (int j = 0; j < 4; ++j) c[j] = cs[j];
    float4 xv = *(const float4*)&xT[(size_t)t * Dd + tid * 4];
    float part[4];
#pragma unroll
    for (int cc = 0; cc < 4; ++cc) {
        float4 wv = *(const float4*)&cb[(size_t)c[cc] * Dd + tid * 4];
        part[cc] = xv.x * wv.x + xv.y * wv.y + xv.z * wv.z + xv.w * wv.w;
    }
#pragma unroll
    for (int cc = 0; cc < 4; ++cc)
#pragma unroll
        for (int off = 32; off; off >>= 1) part[cc] += __shfl_down(part[cc], off, 64);
    if ((tid & 63) == 0)
#pragma unroll
        for (int cc = 0; cc < 4; ++cc) red[tid >> 6][cc] = part[cc];
    __syncthreads();
    if (tid == 0) {
        float bs = 1e30f;
        int bi = 0x7FFFFFFF;
#pragma unroll
        for (int cc = 0; cc < 4; ++cc) {
            float cross = red[0][cc] + red[1][cc] + red[2][cc] + red[3][cc];
            float s = fmaf(-2.f, cross, esq[c[cc]]);
            if (s < bs || (s == bs && c[cc] < bi)) { bs = s; bi = c[cc]; }
        }
        fidx[t] = bi;
    }
}

// ---------- gather values -> out ----------
__global__ __launch_bounds__(256) void gather_kernel(const int* __restrict__ fidx,
                                                     const float* __restrict__ values,
                                                     float* __restrict__ out) {
    const int n = threadIdx.x, b = blockIdx.x, dc = blockIdx.y;
    const int row = fidx[b * Nn + n];
    const float* src = values + (size_t)row * Dd + dc * 64;
    float* dst = out + (size_t)b * Dd * Nn + (size_t)dc * 64 * Nn + n;
#pragma unroll
    for (int j = 0; j < 64; j += 4) {
        float4 v = *(const float4*)(src + j);
        dst[(j + 0) * Nn] = v.x;
        dst[(j + 1) * Nn] = v.y;
        dst[(j + 2) * Nn] = v.z;
        dst[(j + 3) * Nn] = v.w;
    }
}

extern "C" void kernel_launch(void* const* d_in, const int* in_sizes, int n_in,
                              void* d_out, int out_size, void* d_ws, size_t ws_size,
                              hipStream_t stream) {
    const float* x = (const float*)d_in[0];
    const float* cb = (const float*)d_in[1];
    const float* vals = (const float*)d_in[2];
    float* out = (float*)d_out;

    // ws: [Apk 4M][Bpk 8M][pad->16M][esq 32K][cand 8M][fidx 16K] = 24.28 MB.
    // bigws: xT gets its own 16 MB after that (40.3 MB) and prep fills it;
    // else xT aliases the first 16 MB and is filled post-dist by transx.
    char* p = (char*)d_ws;
    uchar* Apk = (uchar*)p;
    uchar* Bpk = (uchar*)(p + ((size_t)4 << 20));
    float* esq = (float*)(p + ((size_t)16 << 20));
    u64* cand = (u64*)(p + ((size_t)16 << 20) + Kk * 4);
    int* fidx = (int*)(p + ((size_t)16 << 20) + Kk * 4 + (size_t)Mm * NCAND * 8);
    const size_t base = ((size_t)16 << 20) + Kk * 4 + (size_t)Mm * NCAND * 8 + Mm * 4;
    const bool bigws = ws_size >= base + ((size_t)16 << 20);
    float* xT = bigws ? (float*)(p + base) : (float*)d_ws;

    prep_kernel<<<1024, 256, 0, stream>>>(x, cb, Apk, Bpk, esq,
                                          bigws ? xT : nullptr);
    mfma_dist_kernel<<<dim3(32, 16), 512, 0, stream>>>(Apk, Bpk, esq, cand);
    if (!bigws) transx_kernel<<<dim3(Bb, 32), 256, 0, stream>>>(x, xT);
    selres_kernel<<<Mm, 256, 0, stream>>>(cand, xT, cb, esq, fidx);
    gather_kernel<<<dim3(Bb, Dd / 64), 256, 0, stream>>>(fidx, vals, out);
}

// Round 11
// 170.886 us; speedup vs baseline: 1.0221x; 1.0221x over previous
//
#include <hip/hip_runtime.h>
#include <cstdint>

// VectorQuantizer: x[16,1024,16,16] f32, codebook[1,8192,1024], values[1,8192,1024]
// Round 18 == Round 17 (broker timeout; wave-per-token selres desk-audited, held).
// r15 HW baseline: passed, absmax 0.0, total 174.7 us, dist 44.0 us.
// r17 change under test: wave-per-token selres -- 512 blocks x 8 waves, one
// token per wave fully in-register: 4 cands/lane -> 4x {lane-min4, wave u64
// butterfly min (DPP ror1/2/4/8 + shfl16/32), invalidate} -> wave-uniform top-4
// -> coalesced rescore (16 floats/lane) -> f32 butterfly sum. No LDS/barriers/
// serial sections. dist: r15 single-barrier loop, HW-verified, untouched.

constexpr int Dd = 1024;   // feature dim (GEMM K)
constexpr int Nn = 256;    // tokens per batch
constexpr int Bb = 16;     // batch
constexpr int Kk = 8192;   // codes (GEMM N)
constexpr int Mm = 4096;   // tokens (GEMM M)
constexpr int STAGES = Dd / 64;     // 16 x 64B K-chunks (kb index)
constexpr int NITER = STAGES / 2;   // 8 main-loop iterations, 128B K per iter
constexpr int NCHUNK = Kk / 64;     // 128 chunks of 64 codes
constexpr int NCAND = NCHUNK * 2;   // 256 candidates per token
constexpr float QS = 24.0f;         // quant scale
constexpr float SC2 = 2.0f / (QS * QS);

typedef __attribute__((ext_vector_type(4))) int vi4;       // 16 i8 = 4 VGPRs
typedef unsigned long long u64;
typedef unsigned char uchar;

__device__ __forceinline__ void gload16(const void* g, void* l) {
    // async global->LDS; lds dest = wave-uniform base + lane*16 (verified r2-r5)
    __builtin_amdgcn_global_load_lds((const __attribute__((address_space(1))) uint32_t*)g,
                                     (__attribute__((address_space(3))) uint32_t*)l, 16, 0, 0);
}

// DPP row_ror:N within 16-lane rows (VALU-rate cross-lane; all lanes active).
template <int CTRL>
__device__ __forceinline__ uint32_t rot16(uint32_t v) {
    return (uint32_t)__builtin_amdgcn_update_dpp(0, (int)v, CTRL, 0xF, 0xF, true);
}
template <int CTRL>
__device__ __forceinline__ u64 rot16_64(u64 v) {
    uint32_t lo = rot16<CTRL>((uint32_t)v);
    uint32_t hi = rot16<CTRL>((uint32_t)(v >> 32));
    return ((u64)hi << 32) | lo;
}

__device__ __forceinline__ void mm2u(uint32_t& a, uint32_t& b) {  // sort pair asc
    uint32_t lo = a < b ? a : b;
    uint32_t hi = a < b ? b : a;
    a = lo; b = hi;
}
// merge sorted pairs: (a1,a2) <- top-2 (smallest) of {a1,a2,b1,b2}
__device__ __forceinline__ void merge2u(uint32_t& a1, uint32_t& a2, uint32_t b1,
                                        uint32_t b2) {
    uint32_t t1 = a1 < b1 ? a1 : b1;
    uint32_t hi = a1 < b1 ? b1 : a1;
    uint32_t l2 = a2 < b2 ? a2 : b2;
    a2 = hi < l2 ? hi : l2;
    a1 = t1;
}

__device__ __forceinline__ int q8(float v) {  // round-to-nearest, clamp [-127,127]
    int qi = (int)rintf(v * QS);
    qi = qi > 127 ? 127 : (qi < -127 ? -127 : qi);
    return qi & 0xFF;
}
__device__ __forceinline__ int pk4i(float a, float b, float c, float d) {
    return q8(a) | (q8(b) << 8) | (q8(c) << 16) | (q8(d) << 24);
}

// Fragment-order packed layout (A and B identical; verified-symmetric for the
// 16x16 family): P[(g*16 + kb)*64 + lane]*16B, g = row>>4, kb = k>>6,
// lane = (row&15) | (q<<4), q = (k>>4)&3, byte j = k&15.

// ---------- prep ----------
// grid 1024: [0,512) cb->Bpk + esq; [512,1024) x->Apk (+xT when non-null)
__global__ __launch_bounds__(256) void prep_kernel(const float* __restrict__ x,
                                                   const float* __restrict__ cb,
                                                   uchar* __restrict__ Apk,
                                                   uchar* __restrict__ Bpk,
                                                   float* __restrict__ esq,
                                                   float* __restrict__ xT) {
    const int tid = threadIdx.x;
    if (blockIdx.x < 512) {  // codebook: 16 codes/block; thread=(rl 4b hi, seg 4b lo)
        const int rl = tid >> 4, seg = tid & 15;   // seg == kb
        const int code = blockIdx.x * 16 + rl;
        const float* src = cb + (size_t)code * Dd + seg * 64;
        float v[64];
        float ss = 0.f;
#pragma unroll
        for (int j = 0; j < 64; j += 4) {
            float4 f = *(const float4*)&src[j];
            v[j] = f.x; v[j + 1] = f.y; v[j + 2] = f.z; v[j + 3] = f.w;
            ss += f.x * f.x + f.y * f.y + f.z * f.z + f.w * f.w;
        }
#pragma unroll
        for (int off = 8; off; off >>= 1) ss += __shfl_down(ss, off, 16);
        if (seg == 0) esq[code] = ss;
        const int g = code >> 4, rlane = code & 15;
#pragma unroll
        for (int q = 0; q < 4; ++q) {
            int o[4];
#pragma unroll
            for (int w4 = 0; w4 < 4; ++w4) {
                const int j = q * 16 + w4 * 4;
                o[w4] = pk4i(v[j], v[j + 1], v[j + 2], v[j + 3]);
            }
            *(uint4*)&Bpk[((size_t)(g * 16 + seg) * 64 + (rlane | (q << 4))) * 16] =
                *(const uint4*)o;
        }
    } else {  // x -> Apk (+ xT): block=(b, d-chunk of 32), thread=n
        const int bb = blockIdx.x - 512;
        const int b = bb >> 5, d0 = (bb & 31) * 32, n = tid;
        const int t = b * 256 + n;
        const float* xb = x + (size_t)b * Dd * Nn + n;
        const int g = t >> 4, rlane = t & 15, kb = d0 >> 6, qbase = (d0 & 32) >> 4;
        float v[32];
#pragma unroll
        for (int jj = 0; jj < 32; ++jj) v[jj] = xb[(size_t)(d0 + jj) * Nn];
#pragma unroll
        for (int h = 0; h < 2; ++h) {
            int o[4];
#pragma unroll
            for (int w4 = 0; w4 < 4; ++w4) {
                const int j = h * 16 + w4 * 4;
                o[w4] = pk4i(v[j], v[j + 1], v[j + 2], v[j + 3]);
            }
            *(uint4*)&Apk[((size_t)(g * 16 + kb) * 64 + (rlane | ((qbase + h) << 4))) * 16] =
                *(const uint4*)o;
        }
        if (xT) {  // bigws only: write the already-loaded slice to xT
            float* row = xT + (size_t)t * Dd + d0;
#pragma unroll
            for (int jj = 0; jj < 32; jj += 4) {
                float4 f;
                f.x = v[jj]; f.y = v[jj + 1]; f.z = v[jj + 2]; f.w = v[jj + 3];
                *(float4*)&row[jj] = f;
            }
        }
    }
}

// ---------- x -> xT fp32 (fallback path, AFTER dist; aliases Apk/Bpk region) ----------
__global__ __launch_bounds__(256) void transx_kernel(const float* __restrict__ x,
                                                     float* __restrict__ xT) {
    const int n = threadIdx.x, b = blockIdx.x, d0 = blockIdx.y * 32;
    const float* xb = x + (size_t)b * Dd * Nn + n;
    float* row = xT + (size_t)(b * Nn + n) * Dd + d0;
#pragma unroll
    for (int jj = 0; jj < 8; ++jj) {
        float4 v;
        v.x = xb[(size_t)(d0 + jj * 4 + 0) * Nn];
        v.y = xb[(size_t)(d0 + jj * 4 + 1) * Nn];
        v.z = xb[(size_t)(d0 + jj * 4 + 2) * Nn];
        v.w = xb[(size_t)(d0 + jj * 4 + 3) * Nn];
        *(float4*)&row[jj * 4] = v;
    }
}

// ---------- i8 MFMA distance: 256x256 tile, single-barrier iterations ----------
// grid (32, 16), 512 threads = 8 waves (wm in [0,2), wn in [0,4)).
// Wave owns a 128x64 output tile = 8x4 fragments of 16x16x64 MFMA.
// LDS: double buffer x 2 K-tiles(64B) x 16 groups x 1KB for A and for B = 128 KB.
// Main loop: 8 iters, 128B K each, ONE barrier per iter (HW-verified r15/r16):
//   vmcnt(0) -> s_barrier -> sched_barrier(0) -> issue 8 gloads for iter i+1 ->
//   24 ds_read_b128 + 64 MFMA, setprio(1).
__global__ __launch_bounds__(512, 2) void mfma_dist_kernel(const uchar* __restrict__ Apk,
                                                           const uchar* __restrict__ Bpk,
                                                           const float* __restrict__ esq,
                                                           u64* __restrict__ cand) {
    __shared__ uchar As[2 * 2 * 16 * 1024];  // [buf][kt][group][1KB]
    __shared__ uchar Bs[2 * 2 * 16 * 1024];

    const int tid = threadIdx.x, lane = tid & 63, w = tid >> 6;
    const int wm = w >> 2, wn = w & 3;
    const int nBase = blockIdx.x * 256, mBase = blockIdx.y * 256;
    const int gA = blockIdx.y * 16, gB = blockIdx.x * 16;  // global 16-row group bases

    vi4 acc[8][4];
#pragma unroll
    for (int i = 0; i < 8; ++i)
#pragma unroll
        for (int j = 0; j < 4; ++j) acc[i][j] = (vi4)0;

    // Staging assignment: waves 0-3 stage A groups (w&3)*4..+3, waves 4-7 stage B.
    const uchar* gmat = (w < 4) ? Apk : Bpk;
    const int gBase = ((w < 4) ? gA : gB) + (w & 3) * 4;
    const uchar* gsrc = gmat + (size_t)gBase * 16384 + (size_t)lane * 16;
    uchar* swave = ((w < 4) ? As : Bs) + (w & 3) * 4096;  // + buf*32768 + kt*16384 + r*1024

    // issue both kt sub-tiles of iteration it into buffer buf
    auto stage_iter = [&](int buf, int it) {
#pragma unroll
        for (int kt = 0; kt < 2; ++kt) {
            const int kb = 2 * it + kt;
            uchar* ldst = swave + buf * 32768 + kt * 16384;
#pragma unroll
            for (int r = 0; r < 4; ++r)
                gload16(gsrc + (size_t)(r * 16 + kb) * 1024, ldst + r * 1024);
        }
    };

    auto compute = [&](int buf, int kt) {
        const uchar* ab = As + buf * 32768 + kt * 16384;
        const uchar* bb = Bs + buf * 32768 + kt * 16384;
        vi4 af[8], bf[4];
#pragma unroll
        for (int mi = 0; mi < 8; ++mi)
            af[mi] = *(const vi4*)&ab[((wm * 8 + mi) * 64 + lane) * 16];
#pragma unroll
        for (int ni = 0; ni < 4; ++ni)
            bf[ni] = *(const vi4*)&bb[((wn * 4 + ni) * 64 + lane) * 16];
#pragma unroll
        for (int mi = 0; mi < 8; ++mi)
#pragma unroll
            for (int ni = 0; ni < 4; ++ni)
                acc[mi][ni] = __builtin_amdgcn_mfma_i32_16x16x64_i8(
                    af[mi], bf[ni], acc[mi][ni], 0, 0, 0);
    };

    // prologue: stage iter 0 into buf 0
    stage_iter(0, 0);

    for (int i = 0; i < NITER; ++i) {
        const int buf = i & 1;
        asm volatile("s_waitcnt vmcnt(0)" ::: "memory");  // iter i's loads done
        __builtin_amdgcn_s_barrier();                     // publish to all waves
        __builtin_amdgcn_sched_barrier(0);                // pin everything below
        if (i + 1 < NITER) stage_iter(buf ^ 1, i + 1);    // post-barrier: WAR-safe
        __builtin_amdgcn_s_setprio(1);
        compute(buf, 0);
        compute(buf, 1);
        __builtin_amdgcn_s_setprio(0);
    }

    // Epilogue. C/D: col = lane&15 (+ni*16), row = (lane>>4)*4 + reg.
    // score = max(esq - (2/s^2)*dot, 0) >= 0 -> raw bits order = float order.
    // 32-bit key = (score_bits & ~0x3F) | (ni*16 | lane&15).
    const int chunk = blockIdx.x * 4 + wn;
    const uint32_t cbase = (uint32_t)(nBase + wn * 64);
    float e4[4];
#pragma unroll
    for (int ni = 0; ni < 4; ++ni) e4[ni] = esq[cbase + ni * 16 + (lane & 15)];
#pragma unroll
    for (int mi = 0; mi < 8; ++mi) {
#pragma unroll
        for (int reg = 0; reg < 4; ++reg) {
            uint32_t p[4];
#pragma unroll
            for (int ni = 0; ni < 4; ++ni) {
                float s = fmaxf(fmaf(-SC2, (float)acc[mi][ni][reg], e4[ni]), 0.f);
                p[ni] = (__float_as_uint(s) & 0xFFFFFFC0u) |
                        (uint32_t)(ni * 16 + (lane & 15));
            }
            mm2u(p[0], p[1]); mm2u(p[2], p[3]);
            merge2u(p[0], p[1], p[2], p[3]);
            uint32_t t1 = p[0], t2 = p[1];
            // DPP rotate-merge within the 16-lane row (disjoint windows 1,2,4,8)
            { uint32_t o1 = rot16<0x121>(t1), o2 = rot16<0x121>(t2);
              merge2u(t1, t2, o1, o2); }
            { uint32_t o1 = rot16<0x122>(t1), o2 = rot16<0x122>(t2);
              merge2u(t1, t2, o1, o2); }
            { uint32_t o1 = rot16<0x124>(t1), o2 = rot16<0x124>(t2);
              merge2u(t1, t2, o1, o2); }
            { uint32_t o1 = rot16<0x128>(t1), o2 = rot16<0x128>(t2);
              merge2u(t1, t2, o1, o2); }
            if ((lane & 15) == 0) {
                const int t = mBase + wm * 128 + mi * 16 + (lane >> 4) * 4 + reg;
                cand[(size_t)t * NCAND + chunk * 2 + 0] =
                    ((u64)(t1 & 0xFFFFFFC0u) << 32) | (cbase + (t1 & 63u));
                cand[(size_t)t * NCAND + chunk * 2 + 1] =
                    ((u64)(t2 & 0xFFFFFFC0u) << 32) | (cbase + (t2 & 63u));
            }
        }
    }
}

// ---------- wave-per-token select(top-4 of 256) + exact fp32 rescore ----------
// grid Mm/8 = 512, 512 threads = 8 waves; wave w owns token t = bx*8 + w.
// No LDS, no barriers, no serial sections. 4 cands/lane; 4 rounds of
// {lane-min4, wave u64 butterfly-min, invalidate} give wave-uniform top-4;
// rescore with wave-uniform cb rows (coalesced 16 floats/lane) + butterfly sum.
__global__ __launch_bounds__(512) void selres_kernel(const u64* __restrict__ cand,
                                                     const float* __restrict__ xT,
                                                     const float* __restrict__ cb,
                                                     const float* __restrict__ esq,
                                                     int* __restrict__ fidx) {
    const int tid = threadIdx.x, lane = tid & 63, w = tid >> 6;
    const int t = blockIdx.x * 8 + w;
    const u64* cp = cand + (size_t)t * NCAND;
    u64 c0 = cp[lane], c1 = cp[lane + 64], c2 = cp[lane + 128], c3 = cp[lane + 192];
    int cs[4];
#pragma unroll
    for (int rd = 0; rd < 4; ++rd) {
        u64 a01 = c0 < c1 ? c0 : c1;
        u64 a23 = c2 < c3 ? c2 : c3;
        u64 m = a01 < a23 ? a01 : a23;
        { u64 o = rot16_64<0x121>(m); m = m < o ? m : o; }
        { u64 o = rot16_64<0x122>(m); m = m < o ? m : o; }
        { u64 o = rot16_64<0x124>(m); m = m < o ? m : o; }
        { u64 o = rot16_64<0x128>(m); m = m < o ? m : o; }
        { u64 o = __shfl_xor(m, 16, 64); m = m < o ? m : o; }
        { u64 o = __shfl_xor(m, 32, 64); m = m < o ? m : o; }
        cs[rd] = (int)(uint32_t)m;            // wave-uniform
        if (c0 == m) c0 = ~0ULL;              // keys unique per token
        else if (c1 == m) c1 = ~0ULL;
        else if (c2 == m) c2 = ~0ULL;
        else if (c3 == m) c3 = ~0ULL;
    }
    // exact fp32 rescore: 16 floats/lane, 4 coalesced float4 strips
    const float* xrow = xT + (size_t)t * Dd;
    float part[4] = {0.f, 0.f, 0.f, 0.f};
#pragma unroll
    for (int jj = 0; jj < 4; ++jj) {
        const int off = jj * 256 + lane * 4;
        float4 xv = *(const float4*)&xrow[off];
#pragma unroll
        for (int cc = 0; cc < 4; ++cc) {
            float4 wv = *(const float4*)&cb[(size_t)cs[cc] * Dd + off];
            part[cc] += xv.x * wv.x + xv.y * wv.y + xv.z * wv.z + xv.w * wv.w;
        }
    }
#pragma unroll
    for (int cc = 0; cc < 4; ++cc)
#pragma unroll
        for (int off = 1; off < 64; off <<= 1)
            part[cc] += __shfl_xor(part[cc], off, 64);
    if (lane == 0) {
        float bs = 1e30f;
        int bi = 0x7FFFFFFF;
#pragma unroll
        for (int cc = 0; cc < 4; ++cc) {
            float s = fmaf(-2.f, part[cc], esq[cs[cc]]);
            if (s < bs || (s == bs && cs[cc] < bi)) { bs = s; bi = cs[cc]; }
        }
        fidx[t] = bi;
    }
}

// ---------- gather values -> out ----------
__global__ __launch_bounds__(256) void gather_kernel(const int* __restrict__ fidx,
                                                     const float* __restrict__ values,
                                                     float* __restrict__ out) {
    const int n = threadIdx.x, b = blockIdx.x, dc = blockIdx.y;
    const int row = fidx[b * Nn + n];
    const float* src = values + (size_t)row * Dd + dc * 64;
    float* dst = out + (size_t)b * Dd * Nn + (size_t)dc * 64 * Nn + n;
#pragma unroll
    for (int j = 0; j < 64; j += 4) {
        float4 v = *(const float4*)(src + j);
        dst[(j + 0) * Nn] = v.x;
        dst[(j + 1) * Nn] = v.y;
        dst[(j + 2) * Nn] = v.z;
        dst[(j + 3) * Nn] = v.w;
    }
}

extern "C" void kernel_launch(void* const* d_in, const int* in_sizes, int n_in,
                              void* d_out, int out_size, void* d_ws, size_t ws_size,
                              hipStream_t stream) {
    const float* x = (const float*)d_in[0];
    const float* cb = (const float*)d_in[1];
    const float* vals = (const float*)d_in[2];
    float* out = (float*)d_out;

    // ws: [Apk 4M][Bpk 8M][pad->16M][esq 32K][cand 8M][fidx 16K] = 24.28 MB.
    // bigws: xT gets its own 16 MB after that (40.3 MB) and prep fills it;
    // else xT aliases the first 16 MB and is filled post-dist by transx.
    char* p = (char*)d_ws;
    uchar* Apk = (uchar*)p;
    uchar* Bpk = (uchar*)(p + ((size_t)4 << 20));
    float* esq = (float*)(p + ((size_t)16 << 20));
    u64* cand = (u64*)(p + ((size_t)16 << 20) + Kk * 4);
    int* fidx = (int*)(p + ((size_t)16 << 20) + Kk * 4 + (size_t)Mm * NCAND * 8);
    const size_t base = ((size_t)16 << 20) + Kk * 4 + (size_t)Mm * NCAND * 8 + Mm * 4;
    const bool bigws = ws_size >= base + ((size_t)16 << 20);
    float* xT = bigws ? (float*)(p + base) : (float*)d_ws;

    prep_kernel<<<1024, 256, 0, stream>>>(x, cb, Apk, Bpk, esq,
                                          bigws ? xT : nullptr);
    mfma_dist_kernel<<<dim3(32, 16), 512, 0, stream>>>(Apk, Bpk, esq, cand);
    if (!bigws) transx_kernel<<<dim3(Bb, 32), 256, 0, stream>>>(x, xT);
    selres_kernel<<<Mm / 8, 512, 0, stream>>>(cand, xT, cb, esq, fidx);
    gather_kernel<<<dim3(Bb, Dd / 64), 256, 0, stream>>>(fidx, vals, out);
}